// Round 1
// baseline (10388.732 us; speedup 1.0000x reference)
//
#include <hip/hip_runtime.h>
#include <hip/hip_fp16.h>

#define SEQL 4096
#define EMBD 512
#define HIDD 2048
#define NCH  256
#define WCOL 2560   // EMB + HID

typedef _Float16 half8_t __attribute__((ext_vector_type(8)));
typedef _Float16 half2_t __attribute__((ext_vector_type(2)));
typedef float    float4_t __attribute__((ext_vector_type(4)));

#if __has_builtin(__builtin_amdgcn_fdot2)
__device__ __forceinline__ float fdot2u(unsigned a, unsigned b, float c) {
  return __builtin_amdgcn_fdot2(__builtin_bit_cast(half2_t, a),
                                __builtin_bit_cast(half2_t, b), c, false);
}
#else
__device__ __forceinline__ float fdot2u(unsigned a, unsigned b, float c) {
  half2_t ha = __builtin_bit_cast(half2_t, a), hb = __builtin_bit_cast(half2_t, b);
  return c + (float)ha.x * (float)hb.x + (float)ha.y * (float)hb.y;
}
#endif

__device__ __forceinline__ float sigm_f(float x)  { return 1.f / (1.f + __expf(-x)); }
__device__ __forceinline__ float tanh_f(float x)  { return 1.f - 2.f / (__expf(2.f * x) + 1.f); }

// ---------------------------------------------------------------------------
// prep: f32->f16 conversions (emb gather, stacked recurrent-GEMM B, Wy) and
//       zeroing of the h-exchange tag buffer (must re-run every launch).
// ---------------------------------------------------------------------------
__global__ void prep_kernel(const int* __restrict__ seq, const float* __restrict__ emb,
                            const float* __restrict__ Wf, const float* __restrict__ Wi,
                            const float* __restrict__ Wo, const float* __restrict__ Wc,
                            const float* __restrict__ Wy,
                            _Float16* __restrict__ emb16, _Float16* __restrict__ Wst16,
                            _Float16* __restrict__ Wy16, unsigned* __restrict__ hstage)
{
  const long nEmb = (long)SEQL * EMBD;       // 2M
  const long nWst = (long)4 * HIDD * EMBD;   // 4M
  const long nWy  = (long)NCH * HIDD;        // 512K
  const long nHs  = 2 * HIDD;
  const long total = nEmb + nWst + nWy + nHs;
  long stride = (long)gridDim.x * blockDim.x;
  for (long i = (long)blockIdx.x * blockDim.x + threadIdx.x; i < total; i += stride) {
    if (i < nEmb) {
      long t = i >> 9, e = i & 511;
      emb16[i] = (_Float16)emb[(long)seq[t] * EMBD + e];
    } else if (i < nEmb + nWst) {
      long j = i - nEmb;
      long row = j >> 9, k = j & 511;
      long r = row >> 11, jr = row & 2047;
      const float* W = (r == 0) ? Wf : (r == 1) ? Wi : (r == 2) ? Wo : Wc;
      Wst16[j] = (_Float16)W[jr * WCOL + k];
    } else if (i < nEmb + nWst + nWy) {
      long j = i - nEmb - nWst;
      Wy16[j] = (_Float16)Wy[j];             // Wy is row-major 256x2048, 1:1 copy
    } else {
      hstage[i - nEmb - nWst - nWy] = 0u;
    }
  }
}

// ---------------------------------------------------------------------------
// gemm_bt: C[M][N] = A[M][K] * B[N][K]^T   (both K-contiguous f16, MFMA 16x16x32)
// MODE 0: store f16 to C16 (ldc=N).  MODE 1: store f32 + bias to Cf (ldc=N).
// 128x128 tile, BK=32, 256 threads (4 waves as 2x2 of 64x64).
// ---------------------------------------------------------------------------
template<int K, int MODE>
__global__ __launch_bounds__(256) void gemm_bt(const _Float16* __restrict__ A,
                                               const _Float16* __restrict__ B,
                                               _Float16* __restrict__ C16,
                                               float* __restrict__ Cf,
                                               const float* __restrict__ bias, int N)
{
  __shared__ _Float16 At[128 * 32];
  __shared__ _Float16 Bt[128 * 32];
  const int tid = threadIdx.x;
  const int w = tid >> 6, lane = tid & 63;
  const int wm = w >> 1, wn = w & 1;
  const int lr = lane & 15, kg = lane >> 4;
  const long tm = (long)blockIdx.y * 128;
  const long tn = (long)blockIdx.x * 128;

  float4_t acc[4][4];
#pragma unroll
  for (int a = 0; a < 4; a++)
#pragma unroll
    for (int b = 0; b < 4; b++) acc[a][b] = (float4_t)0.f;

  for (int kt = 0; kt < K; kt += 32) {
    __syncthreads();
#pragma unroll
    for (int s = 0; s < 2; s++) {
      int l = s * 256 + tid;
      int row = l >> 2, ks = (l & 3) * 8;
      *(uint4*)&At[row * 32 + ks] = *(const uint4*)&A[(tm + row) * (long)K + kt + ks];
      *(uint4*)&Bt[row * 32 + ks] = *(const uint4*)&B[(tn + row) * (long)K + kt + ks];
    }
    __syncthreads();
    half8_t af[4], bf[4];
#pragma unroll
    for (int mi = 0; mi < 4; mi++) af[mi] = *(const half8_t*)&At[(wm * 64 + mi * 16 + lr) * 32 + kg * 8];
#pragma unroll
    for (int ni = 0; ni < 4; ni++) bf[ni] = *(const half8_t*)&Bt[(wn * 64 + ni * 16 + lr) * 32 + kg * 8];
#pragma unroll
    for (int mi = 0; mi < 4; mi++)
#pragma unroll
      for (int ni = 0; ni < 4; ni++)
        acc[mi][ni] = __builtin_amdgcn_mfma_f32_16x16x32_f16(af[mi], bf[ni], acc[mi][ni], 0, 0, 0);
  }

#pragma unroll
  for (int mi = 0; mi < 4; mi++)
#pragma unroll
    for (int ni = 0; ni < 4; ni++)
#pragma unroll
      for (int i = 0; i < 4; i++) {
        long gm = tm + wm * 64 + mi * 16 + kg * 4 + i;
        long gn = tn + wn * 64 + ni * 16 + lr;
        float v = acc[mi][ni][i];
        if (MODE == 0) C16[gm * (long)N + gn] = (_Float16)v;
        else           Cf[gm * (long)N + gn] = v + bias[gn];
      }
}

// ---------------------------------------------------------------------------
// lstm_seq: persistent scan. 256 WGs x 512 threads. WG g owns hidden units
// g*8..g*8+7 (all 4 gates = 32 rows of stacked Whh, f16 in VGPRs: 64 regs/lane).
// Wave layout: wave w has rows 4w..4w+3; 16 lanes per row (hsub=lane&15).
// Lane's k slice: k = it*64 + hsub*4 + {0..3}, it = 0..31.
// h exchange: hstage[2][2048] of (f16 h | tag<<16) dwords, agent-scope relaxed.
// ---------------------------------------------------------------------------
__global__ __launch_bounds__(512) void lstm_seq(
    const _Float16* __restrict__ xq,   // [SEQ][4*HID] gate-major
    const float* __restrict__ Wf, const float* __restrict__ Wi,
    const float* __restrict__ Wo, const float* __restrict__ Wc,
    const float* __restrict__ bfp, const float* __restrict__ bip,
    const float* __restrict__ bop, const float* __restrict__ bcp,
    unsigned* __restrict__ hstage,
    _Float16* __restrict__ H16,        // [SEQ][HID]
    float* __restrict__ out)
{
  __shared__ unsigned hbuf[HIDD / 2];  // f16 pairs of h_{t-1}
  __shared__ float gl[32];             // activated gates for this WG

  const int tid  = threadIdx.x;
  const int wave = tid >> 6, lane = tid & 63;
  const int rw   = lane >> 4, hsub = lane & 15;
  const int row_local = wave * 4 + rw;       // 0..31
  const int r  = row_local >> 3;             // gate: 0=f 1=i 2=o 3=c
  const int jj = row_local & 7;
  const int g  = blockIdx.x;
  const int jg = g * 8 + jj;

  const float* Wsel = (r == 0) ? Wf : (r == 1) ? Wi : (r == 2) ? Wo : Wc;
  const float* bsel = (r == 0) ? bfp : (r == 1) ? bip : (r == 2) ? bop : bcp;
  const float* wrow = Wsel + (long)jg * WCOL + EMBD;

  uint2 wreg[32];
#pragma unroll
  for (int it = 0; it < 32; ++it) {
    const float4 wv = *(const float4*)(wrow + it * 64 + hsub * 4);
    half2_t lo = { (_Float16)wv.x, (_Float16)wv.y };
    half2_t hi = { (_Float16)wv.z, (_Float16)wv.w };
    wreg[it].x = __builtin_bit_cast(unsigned, lo);
    wreg[it].y = __builtin_bit_cast(unsigned, hi);
  }
  const float bias = (hsub == 0) ? bsel[jg] : 0.f;

  float c = 0.f;   // cell state lives in wave-0 lanes 0..7

  for (int t = 0; t < SEQL; ++t) {
    // x prefetch (leaders only) — independent of h, issues before the poll
    float xv = 0.f;
    if (hsub == 0) xv = (float)xq[(long)t * 8192 + r * HIDD + g * 8 + jj];

    if (t == 0) {
      hbuf[tid * 2] = 0u; hbuf[tid * 2 + 1] = 0u;   // h_{-1} = 0
    } else {
      const int base = (t & 1) * HIDD + tid * 4;
      const unsigned tg = (unsigned)t;
      unsigned v0, v1, v2, v3; int guard = 0;
      for (;;) {
        v0 = __hip_atomic_load(&hstage[base + 0], __ATOMIC_RELAXED, __HIP_MEMORY_SCOPE_AGENT);
        v1 = __hip_atomic_load(&hstage[base + 1], __ATOMIC_RELAXED, __HIP_MEMORY_SCOPE_AGENT);
        v2 = __hip_atomic_load(&hstage[base + 2], __ATOMIC_RELAXED, __HIP_MEMORY_SCOPE_AGENT);
        v3 = __hip_atomic_load(&hstage[base + 3], __ATOMIC_RELAXED, __HIP_MEMORY_SCOPE_AGENT);
        if ((v0 >> 16) == tg && (v1 >> 16) == tg && (v2 >> 16) == tg && (v3 >> 16) == tg) break;
        if (++guard > (1 << 24)) break;   // emergency escape (never in normal flow)
      }
      hbuf[tid * 2]     = (v0 & 0xffffu) | (v1 << 16);
      hbuf[tid * 2 + 1] = (v2 & 0xffffu) | (v3 << 16);
    }
    __syncthreads();

    // matvec: row dot h over this lane's k slice
    float a0 = 0.f, a1 = 0.f, a2 = 0.f, a3 = 0.f;
#pragma unroll
    for (int it = 0; it < 32; ++it) {
      const uint2 hv = *(const uint2*)&hbuf[it * 32 + hsub * 2];
      if (it & 1) { a2 = fdot2u(wreg[it].x, hv.x, a2); a3 = fdot2u(wreg[it].y, hv.y, a3); }
      else        { a0 = fdot2u(wreg[it].x, hv.x, a0); a1 = fdot2u(wreg[it].y, hv.y, a1); }
    }
    float s = (a0 + a1) + (a2 + a3);
    s += __shfl_xor(s, 1, 64);
    s += __shfl_xor(s, 2, 64);
    s += __shfl_xor(s, 4, 64);
    s += __shfl_xor(s, 8, 64);

    if (hsub == 0) {
      const float pre = s + xv + bias;
      gl[row_local] = (r == 3) ? tanh_f(pre) : sigm_f(pre);
    }
    __syncthreads();

    if (tid < 8) {
      const float f  = gl[tid];
      const float ii = gl[8 + tid];
      const float o  = gl[16 + tid];
      const float cg = gl[24 + tid];
      c = f * c + ii * cg;
      const float h = o * tanh_f(c);
      const _Float16 hh = (_Float16)h;
      H16[(long)t * HIDD + g * 8 + tid] = hh;
      const unsigned pk = (unsigned)__builtin_bit_cast(unsigned short, hh) | ((unsigned)(t + 1) << 16);
      __hip_atomic_store(&hstage[((t + 1) & 1) * HIDD + g * 8 + tid], pk,
                         __ATOMIC_RELAXED, __HIP_MEMORY_SCOPE_AGENT);
      if (t == SEQL - 1) {
        out[(long)SEQL * NCH + g * 8 + tid] = h;                 // final h
        out[(long)SEQL * NCH + HIDD + g * 8 + tid] = c;          // final c
      }
    }
  }
}

// ---------------------------------------------------------------------------
extern "C" void kernel_launch(void* const* d_in, const int* in_sizes, int n_in,
                              void* d_out, int out_size, void* d_ws, size_t ws_size,
                              hipStream_t stream) {
  const int*   seq = (const int*)d_in[0];
  const float* emb = (const float*)d_in[1];
  const float* Wf  = (const float*)d_in[2];
  const float* bf_ = (const float*)d_in[3];
  const float* Wi  = (const float*)d_in[4];
  const float* bi_ = (const float*)d_in[5];
  const float* Wo  = (const float*)d_in[6];
  const float* bo_ = (const float*)d_in[7];
  const float* Wc  = (const float*)d_in[8];
  const float* bc_ = (const float*)d_in[9];
  const float* Wy  = (const float*)d_in[10];
  const float* by  = (const float*)d_in[11];
  float* out = (float*)d_out;

  char* ws = (char*)d_ws;
  _Float16* xq     = (_Float16*)(ws);                          // 64 MB: [4096][8192]
  _Float16* emb16  = (_Float16*)(ws + (64ll << 20));           //  4 MB: [4096][512]
  _Float16* Wst16  = (_Float16*)(ws + (68ll << 20));           //  8 MB: [8192][512]
  _Float16* Wy16   = (_Float16*)(ws + (76ll << 20));           //  1 MB: [256][2048]
  _Float16* H16    = (_Float16*)(ws + (77ll << 20));           // 16 MB: [4096][2048]
  unsigned* hstage = (unsigned*)(ws + (93ll << 20));           // 16 KB: [2][2048]

  prep_kernel<<<2048, 256, 0, stream>>>(seq, emb, Wf, Wi, Wo, Wc, Wy,
                                        emb16, Wst16, Wy16, hstage);

  dim3 g1(8192 / 128, 4096 / 128);   // N tiles x M tiles
  gemm_bt<EMBD, 0><<<g1, 256, 0, stream>>>(emb16, Wst16, xq, nullptr, nullptr, 8192);

  lstm_seq<<<256, 512, 0, stream>>>(xq, Wf, Wi, Wo, Wc, bf_, bi_, bo_, bc_,
                                    hstage, H16, out);

  dim3 g2(NCH / 128, 4096 / 128);
  gemm_bt<HIDD, 1><<<g2, 256, 0, stream>>>(H16, Wy16, nullptr, out, by, NCH);
}